// Round 17
// baseline (318.090 us; speedup 1.0000x reference)
//
#include <hip/hip_runtime.h>

// ---------- helpers ----------
static __device__ __forceinline__ unsigned short f2bf(float f) {
    union { float f; unsigned int u; } c; c.f = f;
    unsigned int u = c.u;
    return (unsigned short)((u + 0x7FFFu + ((u >> 16) & 1u)) >> 16);  // RNE
}
static __device__ __forceinline__ float bflo(unsigned int uu) {
    union { unsigned int u; float f; } c; c.u = uu << 16; return c.f;
}
static __device__ __forceinline__ float bfhi(unsigned int uu) {
    union { unsigned int u; float f; } c; c.u = uu & 0xffff0000u; return c.f;
}
static __device__ __forceinline__ unsigned char f2fp8(float f) {
    int enc = __builtin_amdgcn_cvt_pk_fp8_f32(f, f, 0, false);  // OCP e4m3 on gfx950
    return (unsigned char)(enc & 0xff);
}
// real XCD id of the executing wave (gfx950: 0..7) [measured: learn_hip m09]
static __device__ __forceinline__ int xcc_id() {
    unsigned v;
    asm volatile("s_getreg_b32 %0, hwreg(HW_REG_XCC_ID, 0, 32)" : "=s"(v));
    return (int)(v & 7u);
}

typedef __bf16 bf16x8 __attribute__((ext_vector_type(8)));
typedef float  f32x4  __attribute__((ext_vector_type(4)));
typedef float  f32x2  __attribute__((ext_vector_type(2)));

#define SLOT      64
#define SPILLCAP  8192
#define NXCD      8
#define CHUNK     1024

// ---------- 16-feature MLP partial: relu(u_fp8 + v) . w2 ----------
static __device__ __forceinline__ float mlp16(uint4 ua, const float* __restrict__ vf,
                                              const float* __restrict__ w2r) {
    f32x2 d0 = __builtin_amdgcn_cvt_pk_f32_fp8(ua.x, false);
    f32x2 d1 = __builtin_amdgcn_cvt_pk_f32_fp8(ua.x, true);
    f32x2 d2 = __builtin_amdgcn_cvt_pk_f32_fp8(ua.y, false);
    f32x2 d3 = __builtin_amdgcn_cvt_pk_f32_fp8(ua.y, true);
    f32x2 d4 = __builtin_amdgcn_cvt_pk_f32_fp8(ua.z, false);
    f32x2 d5 = __builtin_amdgcn_cvt_pk_f32_fp8(ua.z, true);
    f32x2 d6 = __builtin_amdgcn_cvt_pk_f32_fp8(ua.w, false);
    f32x2 d7 = __builtin_amdgcn_cvt_pk_f32_fp8(ua.w, true);
    float p = 0.0f;
    p = fmaf(fmaxf(d0.x + vf[0],  0.f), w2r[0],  p);
    p = fmaf(fmaxf(d0.y + vf[1],  0.f), w2r[1],  p);
    p = fmaf(fmaxf(d1.x + vf[2],  0.f), w2r[2],  p);
    p = fmaf(fmaxf(d1.y + vf[3],  0.f), w2r[3],  p);
    p = fmaf(fmaxf(d2.x + vf[4],  0.f), w2r[4],  p);
    p = fmaf(fmaxf(d2.y + vf[5],  0.f), w2r[5],  p);
    p = fmaf(fmaxf(d3.x + vf[6],  0.f), w2r[6],  p);
    p = fmaf(fmaxf(d3.y + vf[7],  0.f), w2r[7],  p);
    p = fmaf(fmaxf(d4.x + vf[8],  0.f), w2r[8],  p);
    p = fmaf(fmaxf(d4.y + vf[9],  0.f), w2r[9],  p);
    p = fmaf(fmaxf(d5.x + vf[10], 0.f), w2r[10], p);
    p = fmaf(fmaxf(d5.y + vf[11], 0.f), w2r[11], p);
    p = fmaf(fmaxf(d6.x + vf[12], 0.f), w2r[12], p);
    p = fmaf(fmaxf(d6.y + vf[13], 0.f), w2r[13], p);
    p = fmaf(fmaxf(d7.x + vf[14], 0.f), w2r[14], p);
    p = fmaf(fmaxf(d7.y + vf[15], 0.f), w2r[15], p);
    return p;
}

// ---------- prep3: pack W1->Bt, x->XB bf16, zero degnsp + cursors ----------
__global__ void k_prep3(const float* __restrict__ W1, unsigned short* __restrict__ Bt,
                        const float* __restrict__ x, unsigned short* __restrict__ XB,
                        int* __restrict__ degnsp, int* __restrict__ cursor,
                        int NH4, int N) {
    int idx = blockIdx.x * blockDim.x + threadIdx.x;
    int T = gridDim.x * blockDim.x;

    if (idx < 256 * 128) {
        int j = idx >> 7, k = idx & 127;
        int r = (j < 128) ? k : (128 + k);
        Bt[idx] = f2bf(W1[r * 128 + (j & 127)]);
    }
    if (idx < NXCD) cursor[idx] = 0;

    for (int i = idx; i < NH4; i += T) {
        float4 f = ((const float4*)x)[i];
        ushort4 o;
        o.x = f2bf(f.x); o.y = f2bf(f.y); o.z = f2bf(f.z); o.w = f2bf(f.w);
        ((ushort4*)XB)[i] = o;
    }

    for (int i = idx; i <= N; i += T) degnsp[i] = 0;
}

// ---------- gemm + XCD-LOCAL slot-scatter tail ----------
// gemm: grid (ceil(M/64), 4), acc[4]/wave (proven shape).
// Tail: wave claims 1024-edge chunks from its REAL XCD's cursor; scatters only
// edges with target in its XCD's range using L2-local (workgroup-scope) atomics.
// Every degnsp counter / esrc2 line is touched by exactly one XCD -> L2-local
// atomicity is sound, and lines stay resident until one final writeback.
template <typename IT>
__global__ __launch_bounds__(256) void k_gemmsc(const unsigned short* __restrict__ XB,
                                                const unsigned short* __restrict__ Bt,
                                                const float* __restrict__ b1,
                                                unsigned char* __restrict__ U,
                                                unsigned short* __restrict__ V,
                                                const int* __restrict__ ei,
                                                int* __restrict__ degnsp,
                                                int* __restrict__ cursor,
                                                IT* __restrict__ esrc2,
                                                int* __restrict__ spt,
                                                int* __restrict__ sps,
                                                int M, int E) {
    int wave = threadIdx.x >> 6, lane = threadIdx.x & 63;
    int row0 = blockIdx.x * 64 + wave * 16;
    int col0 = blockIdx.y * 64;
    int lr = lane & 15;
    int lk = (lane >> 4) << 3;

    f32x4 acc[4] = {};
    int arow = row0 + lr;
    bool in = (arow < M);
    const unsigned short* xr = XB + (size_t)arow * 128;

#pragma unroll
    for (int kk = 0; kk < 4; ++kk) {
        int k = kk * 32 + lk;
        bf16x8 a = {};
        if (in) a = *(const bf16x8*)(xr + k);
#pragma unroll
        for (int nf = 0; nf < 4; ++nf) {
            int col = col0 + nf * 16 + lr;
            bf16x8 b = *(const bf16x8*)(Bt + col * 128 + k);
            acc[nf] = __builtin_amdgcn_mfma_f32_16x16x32_bf16(a, b, acc[nf], 0, 0, 0);
        }
    }
    // C/D: col = lane&15, row = (lane>>4)*4 + reg
    int rb = row0 + ((lane >> 4) << 2);
    if (col0 < 128) {
#pragma unroll
        for (int nf = 0; nf < 4; ++nf) {
            int feat = col0 + nf * 16 + lr;
#pragma unroll
            for (int r = 0; r < 4; ++r) {
                int node = rb + r;
                if (node < M) U[(size_t)node * 128 + feat] = f2fp8(acc[nf][r]);
            }
        }
    } else {
#pragma unroll
        for (int nf = 0; nf < 4; ++nf) {
            int feat = col0 + nf * 16 + lr - 128;
            float bias = b1[feat];
#pragma unroll
            for (int r = 0; r < 4; ++r) {
                int node = rb + r;
                if (node < M) V[(size_t)node * 128 + feat] = f2bf(acc[nf][r] + bias);
            }
        }
    }

    // ---- XCD-local slot-scatter tail (per-wave chunk claiming) ----
    int N = M;
    int cls = xcc_id();                            // real XCD of this wave
    int t0 = (int)(((long long)N * cls) >> 3);
    int t1 = (int)(((long long)N * (cls + 1)) >> 3);
    int nchunk = (E + CHUNK - 1) / CHUNK;

    for (;;) {
        int c;
        if (lane == 0) c = atomicAdd(cursor + cls, 1);   // device-scope, ~6k total
        c = __shfl(c, 0);
        if (c >= nchunk) break;
        int e0 = c * CHUNK;
        int e1 = e0 + CHUNK; if (e1 > E) e1 = E;
        for (int e = e0 + lane; e < e1; e += 64) {
            int t = ei[E + e];
            if (t < t0 || t >= t1) continue;             // not this XCD's range
            int s = ei[e];
            // L2-local atomic: counter owned exclusively by this XCD
            int r = __hip_atomic_fetch_add(degnsp + t, 1, __ATOMIC_RELAXED,
                                           __HIP_MEMORY_SCOPE_WORKGROUP);
            if (r < SLOT) {
                esrc2[((size_t)t << 6) + r] = (IT)s;
            } else {
                int sp = atomicAdd(degnsp + N, 1);       // device-scope (rare)
                if (sp < SPILLCAP) { spt[sp] = t; sps[sp] = s; }
            }
        }
    }
}

// ---------- fused (slotted): per-target weights + aggregate + LayerNorm ----------
template <typename IT>
__global__ __launch_bounds__(256) void k_fused_slot(const unsigned char* __restrict__ U,
                                                    const unsigned short* __restrict__ V,
                                                    const unsigned short* __restrict__ XB,
                                                    const int* __restrict__ degnsp,
                                                    const IT* __restrict__ esrc2,
                                                    const int* __restrict__ spt,
                                                    const int* __restrict__ sps,
                                                    const float* __restrict__ W2,
                                                    const float* __restrict__ b2,
                                                    const float* __restrict__ gamma,
                                                    const float* __restrict__ beta,
                                                    float* __restrict__ out, int N) {
    int row = blockIdx.x * 4 + (threadIdx.x >> 6);
    if (row >= N) return;
    int lane = threadIdx.x & 63;
    int el = lane & 7;
    int q  = lane >> 3;

    float w2r[16];
#pragma unroll
    for (int i = 0; i < 16; ++i) w2r[i] = W2[16 * q + i];
    float b2s = b2[0];

    const unsigned short* vp = V + (size_t)row * 128 + 16 * q;
    uint4 va = *(const uint4*)vp;
    uint4 vb = *(const uint4*)(vp + 8);
    float vf[16];
    vf[0]  = bflo(va.x); vf[1]  = bfhi(va.x);
    vf[2]  = bflo(va.y); vf[3]  = bfhi(va.y);
    vf[4]  = bflo(va.z); vf[5]  = bfhi(va.z);
    vf[6]  = bflo(va.w); vf[7]  = bfhi(va.w);
    vf[8]  = bflo(vb.x); vf[9]  = bfhi(vb.x);
    vf[10] = bflo(vb.y); vf[11] = bfhi(vb.y);
    vf[12] = bflo(vb.z); vf[13] = bfhi(vb.z);
    vf[14] = bflo(vb.w); vf[15] = bfhi(vb.w);

    int dg = degnsp[row];
    int st = row << 6;
    int en = st + (dg < SLOT ? dg : SLOT);

    unsigned int xvr = *(const unsigned int*)(XB + (size_t)row * 128 + 2 * lane);
    float a0 = bflo(xvr), a1 = bfhi(xvr);

    for (int g = st; g < en; g += 8) {
        int e = g + el;
        bool val = (e < en);
        int s = val ? (int)esrc2[e] : 0;

        uint4 ua = *(const uint4*)(U + (size_t)s * 128 + 16 * q);
        float p = mlp16(ua, vf, w2r);
        p += __shfl_xor(p, 8);
        p += __shfl_xor(p, 16);
        p += __shfl_xor(p, 32);
        float w = val ? 1.0f / (1.0f + __expf(-(p + b2s))) : 0.0f;

#pragma unroll
        for (int j = 0; j < 8; ++j) {
            float wj = __shfl(w, j);
            int   sj = __shfl(s, j);
            unsigned int xv = *(const unsigned int*)(XB + (size_t)sj * 128 + 2 * lane);
            a0 = fmaf(wj, bflo(xv), a0);
            a1 = fmaf(wj, bfhi(xv), a1);
        }
    }

    // spill edges (correctness net; empty in practice)
    int ns = degnsp[N];
    if (ns > 0) {
        if (ns > SPILLCAP) ns = SPILLCAP;
        for (int i = 0; i < ns; ++i) {
            if (spt[i] == row) {
                int s = sps[i];  // uniform across wave
                uint4 ua = *(const uint4*)(U + (size_t)s * 128 + 16 * q);
                float p = mlp16(ua, vf, w2r);
                p += __shfl_xor(p, 8);
                p += __shfl_xor(p, 16);
                p += __shfl_xor(p, 32);
                float w = 1.0f / (1.0f + __expf(-(p + b2s)));
                unsigned int xv = *(const unsigned int*)(XB + (size_t)s * 128 + 2 * lane);
                a0 = fmaf(w, bflo(xv), a0);
                a1 = fmaf(w, bfhi(xv), a1);
            }
        }
    }

    // LayerNorm
    float sm = a0 + a1;
#pragma unroll
    for (int off = 32; off; off >>= 1) sm += __shfl_xor(sm, off);
    float mu = sm * (1.0f / 128.0f);
    float d0v = a0 - mu, d1v = a1 - mu;
    float qq = d0v * d0v + d1v * d1v;
#pragma unroll
    for (int off = 32; off; off >>= 1) qq += __shfl_xor(qq, off);
    float rstd = rsqrtf(qq * (1.0f / 128.0f) + 1e-5f);
    float2 gg = *(const float2*)(gamma + 2 * lane);
    float2 bb = *(const float2*)(beta + 2 * lane);
    float2 o;
    o.x = d0v * rstd * gg.x + bb.x;
    o.y = d1v * rstd * gg.y + bb.y;
    *(float2*)(out + (size_t)row * 128 + 2 * lane) = o;
}

extern "C" void kernel_launch(void* const* d_in, const int* in_sizes, int n_in,
                              void* d_out, int out_size, void* d_ws, size_t ws_size,
                              hipStream_t stream) {
    const float* x     = (const float*)d_in[0];
    const int*   ei    = (const int*)d_in[1];
    const float* W1    = (const float*)d_in[2];
    const float* b1    = (const float*)d_in[3];
    const float* W2    = (const float*)d_in[4];
    const float* b2    = (const float*)d_in[5];
    const float* gamma = (const float*)d_in[6];
    const float* beta  = (const float*)d_in[7];
    float* out = (float*)d_out;

    const int N = in_sizes[0] / 128;   // 50000
    const int E = in_sizes[1] / 2;     // 800000

    char* w = (char*)d_ws;
    size_t off = 0;
    auto alloc = [&](size_t bytes) {
        char* p = w + off;
        off = (off + bytes + 255) & ~(size_t)255;
        return p;
    };
    unsigned short* Bt = (unsigned short*)alloc(256 * 128 * 2);       // 64 KB
    unsigned char*  U  = (unsigned char*)alloc((size_t)N * 128);      // 6.4 MB
    unsigned short* V  = (unsigned short*)alloc((size_t)N * 128 * 2); // 12.8 MB
    unsigned short* XB = (unsigned short*)alloc((size_t)N * 128 * 2); // 12.8 MB
    int* degnsp = (int*)alloc((size_t)(N + 1) * 4);
    int* cursor = (int*)alloc(NXCD * 4);
    int* spt    = (int*)alloc((size_t)SPILLCAP * 4);
    int* sps    = (int*)alloc((size_t)SPILLCAP * 4);

    bool small_idx = (N <= 65535);
    void* esrc2v;
    if (small_idx) esrc2v = alloc((size_t)N * SLOT * 2);              // 6.4 MB ushort
    else           esrc2v = alloc((size_t)N * SLOT * 4);              // int fallback

    k_prep3<<<2048, 256, 0, stream>>>(W1, Bt, x, XB, degnsp, cursor,
                                      N * 128 / 4, N);

    dim3 ggrid((N + 63) / 64, 4);
    if (small_idx) {
        unsigned short* esrc2 = (unsigned short*)esrc2v;
        k_gemmsc<unsigned short><<<ggrid, 256, 0, stream>>>(XB, Bt, b1, U, V, ei,
                                                            degnsp, cursor, esrc2,
                                                            spt, sps, N, E);
        k_fused_slot<unsigned short><<<(N + 3) / 4, 256, 0, stream>>>(
            U, V, XB, degnsp, esrc2, spt, sps, W2, b2, gamma, beta, out, N);
    } else {
        int* esrc2 = (int*)esrc2v;
        k_gemmsc<int><<<ggrid, 256, 0, stream>>>(XB, Bt, b1, U, V, ei,
                                                 degnsp, cursor, esrc2,
                                                 spt, sps, N, E);
        k_fused_slot<int><<<(N + 3) / 4, 256, 0, stream>>>(
            U, V, XB, degnsp, esrc2, spt, sps, W2, b2, gamma, beta, out, N);
    }
}

// Round 18
// 149.051 us; speedup vs baseline: 2.1341x; 2.1341x over previous
//
#include <hip/hip_runtime.h>

// ---------- helpers ----------
static __device__ __forceinline__ unsigned short f2bf(float f) {
    union { float f; unsigned int u; } c; c.f = f;
    unsigned int u = c.u;
    return (unsigned short)((u + 0x7FFFu + ((u >> 16) & 1u)) >> 16);  // RNE
}
static __device__ __forceinline__ float bflo(unsigned int uu) {
    union { unsigned int u; float f; } c; c.u = uu << 16; return c.f;
}
static __device__ __forceinline__ float bfhi(unsigned int uu) {
    union { unsigned int u; float f; } c; c.u = uu & 0xffff0000u; return c.f;
}
static __device__ __forceinline__ unsigned char f2fp8(float f) {
    int enc = __builtin_amdgcn_cvt_pk_fp8_f32(f, f, 0, false);  // OCP e4m3 on gfx950
    return (unsigned char)(enc & 0xff);
}

typedef __bf16 bf16x8 __attribute__((ext_vector_type(8)));
typedef float  f32x4  __attribute__((ext_vector_type(4)));
typedef float  f32x2  __attribute__((ext_vector_type(2)));

#define SLOT      64
#define SPILLCAP  8192
#define NXCD      8

// ---------- 16-feature MLP partial: relu(u_fp8 + v) . w2 ----------
static __device__ __forceinline__ float mlp16(uint4 ua, const float* __restrict__ vf,
                                              const float* __restrict__ w2r) {
    f32x2 d0 = __builtin_amdgcn_cvt_pk_f32_fp8(ua.x, false);
    f32x2 d1 = __builtin_amdgcn_cvt_pk_f32_fp8(ua.x, true);
    f32x2 d2 = __builtin_amdgcn_cvt_pk_f32_fp8(ua.y, false);
    f32x2 d3 = __builtin_amdgcn_cvt_pk_f32_fp8(ua.y, true);
    f32x2 d4 = __builtin_amdgcn_cvt_pk_f32_fp8(ua.z, false);
    f32x2 d5 = __builtin_amdgcn_cvt_pk_f32_fp8(ua.z, true);
    f32x2 d6 = __builtin_amdgcn_cvt_pk_f32_fp8(ua.w, false);
    f32x2 d7 = __builtin_amdgcn_cvt_pk_f32_fp8(ua.w, true);
    float p = 0.0f;
    p = fmaf(fmaxf(d0.x + vf[0],  0.f), w2r[0],  p);
    p = fmaf(fmaxf(d0.y + vf[1],  0.f), w2r[1],  p);
    p = fmaf(fmaxf(d1.x + vf[2],  0.f), w2r[2],  p);
    p = fmaf(fmaxf(d1.y + vf[3],  0.f), w2r[3],  p);
    p = fmaf(fmaxf(d2.x + vf[4],  0.f), w2r[4],  p);
    p = fmaf(fmaxf(d2.y + vf[5],  0.f), w2r[5],  p);
    p = fmaf(fmaxf(d3.x + vf[6],  0.f), w2r[6],  p);
    p = fmaf(fmaxf(d3.y + vf[7],  0.f), w2r[7],  p);
    p = fmaf(fmaxf(d4.x + vf[8],  0.f), w2r[8],  p);
    p = fmaf(fmaxf(d4.y + vf[9],  0.f), w2r[9],  p);
    p = fmaf(fmaxf(d5.x + vf[10], 0.f), w2r[10], p);
    p = fmaf(fmaxf(d5.y + vf[11], 0.f), w2r[11], p);
    p = fmaf(fmaxf(d6.x + vf[12], 0.f), w2r[12], p);
    p = fmaf(fmaxf(d6.y + vf[13], 0.f), w2r[13], p);
    p = fmaf(fmaxf(d7.x + vf[14], 0.f), w2r[14], p);
    p = fmaf(fmaxf(d7.y + vf[15], 0.f), w2r[15], p);
    return p;
}

// ---------- prep3: pack W1->Bt, x->XB bf16, zero degnsp ----------
__global__ void k_prep3(const float* __restrict__ W1, unsigned short* __restrict__ Bt,
                        const float* __restrict__ x, unsigned short* __restrict__ XB,
                        int* __restrict__ degnsp, int NH4, int N) {
    int idx = blockIdx.x * blockDim.x + threadIdx.x;
    int T = gridDim.x * blockDim.x;

    if (idx < 256 * 128) {
        int j = idx >> 7, k = idx & 127;
        int r = (j < 128) ? k : (128 + k);
        Bt[idx] = f2bf(W1[r * 128 + (j & 127)]);
    }

    for (int i = idx; i < NH4; i += T) {
        float4 f = ((const float4*)x)[i];
        ushort4 o;
        o.x = f2bf(f.x); o.y = f2bf(f.y); o.z = f2bf(f.z); o.w = f2bf(f.w);
        ((ushort4*)XB)[i] = o;
    }

    for (int i = idx; i <= N; i += T) degnsp[i] = 0;
}

// ---------- gemm (2-pass, acc[8]) + XCD-partitioned slot-scatter tail ----------
// grid (ceil(M/64), 2). y=0 -> U fp8 (cols 0..127); y=1 -> V bf16 + b1 (cols 128..255).
// XB is read 2x total (was 4x). Scatter tail identical to R15 (proven 72us shape):
// class c = linear block id & 7 handles targets in range c -> esrc2/degnsp lines
// written by one XCD class, device-scope atomics for rank.
template <typename IT>
__global__ __launch_bounds__(256) void k_gemmsc(const unsigned short* __restrict__ XB,
                                                const unsigned short* __restrict__ Bt,
                                                const float* __restrict__ b1,
                                                unsigned char* __restrict__ U,
                                                unsigned short* __restrict__ V,
                                                const int* __restrict__ ei,
                                                int* __restrict__ degnsp,
                                                IT* __restrict__ esrc2,
                                                int* __restrict__ spt,
                                                int* __restrict__ sps,
                                                int M, int E) {
    int wave = threadIdx.x >> 6, lane = threadIdx.x & 63;
    int row0 = blockIdx.x * 64 + wave * 16;
    int col0 = blockIdx.y * 128;
    int lr = lane & 15;
    int lk = (lane >> 4) << 3;

    f32x4 acc[8];
#pragma unroll
    for (int i = 0; i < 8; ++i) acc[i] = (f32x4){0.f, 0.f, 0.f, 0.f};

    int arow = row0 + lr;
    bool in = (arow < M);
    const unsigned short* xr = XB + (size_t)arow * 128;

#pragma unroll
    for (int kk = 0; kk < 4; ++kk) {
        int k = kk * 32 + lk;
        bf16x8 a = {};
        if (in) a = *(const bf16x8*)(xr + k);
#pragma unroll
        for (int nf = 0; nf < 8; ++nf) {
            int col = col0 + nf * 16 + lr;
            bf16x8 b = *(const bf16x8*)(Bt + col * 128 + k);
            acc[nf] = __builtin_amdgcn_mfma_f32_16x16x32_bf16(a, b, acc[nf], 0, 0, 0);
        }
    }
    // C/D: col = lane&15, row = (lane>>4)*4 + reg
    int rb = row0 + ((lane >> 4) << 2);
    if (blockIdx.y == 0) {
#pragma unroll
        for (int nf = 0; nf < 8; ++nf) {
            int feat = nf * 16 + lr;
#pragma unroll
            for (int r = 0; r < 4; ++r) {
                int node = rb + r;
                if (node < M) U[(size_t)node * 128 + feat] = f2fp8(acc[nf][r]);
            }
        }
    } else {
#pragma unroll
        for (int nf = 0; nf < 8; ++nf) {
            int feat = nf * 16 + lr;
            float bias = b1[feat];
#pragma unroll
            for (int r = 0; r < 4; ++r) {
                int node = rb + r;
                if (node < M) V[(size_t)node * 128 + feat] = f2bf(acc[nf][r] + bias);
            }
        }
    }

    // ---- XCD-partitioned slot-scatter tail (R15-proven) ----
    int nblk = gridDim.x * gridDim.y;
    int lin  = blockIdx.y * gridDim.x + blockIdx.x;
    int cls  = lin & (NXCD - 1);                 // XCD class (heuristic mapping)
    int bidc = lin >> 3;                          // block index within class
    int nbc  = (nblk - cls + NXCD - 1) >> 3;      // blocks in this class
    int tid  = bidc * blockDim.x + (int)threadIdx.x;
    int T    = nbc * blockDim.x;
    int N    = M;
    int t0 = (int)(((long long)N * cls) >> 3);
    int t1 = (int)(((long long)N * (cls + 1)) >> 3);

    for (int e = tid; e < E; e += T) {
        int t = ei[E + e];
        if (t < t0 || t >= t1) continue;          // not this class's target range
        int s = ei[e];
        int r = atomicAdd(degnsp + t, 1);
        if (r < SLOT) {
            esrc2[((size_t)t << 6) + r] = (IT)s;
        } else {
            int sp = atomicAdd(degnsp + N, 1);
            if (sp < SPILLCAP) { spt[sp] = t; sps[sp] = s; }
        }
    }
}

// ---------- fused (slotted): per-target weights + aggregate + LayerNorm ----------
template <typename IT>
__global__ __launch_bounds__(256) void k_fused_slot(const unsigned char* __restrict__ U,
                                                    const unsigned short* __restrict__ V,
                                                    const unsigned short* __restrict__ XB,
                                                    const int* __restrict__ degnsp,
                                                    const IT* __restrict__ esrc2,
                                                    const int* __restrict__ spt,
                                                    const int* __restrict__ sps,
                                                    const float* __restrict__ W2,
                                                    const float* __restrict__ b2,
                                                    const float* __restrict__ gamma,
                                                    const float* __restrict__ beta,
                                                    float* __restrict__ out, int N) {
    int row = blockIdx.x * 4 + (threadIdx.x >> 6);
    if (row >= N) return;
    int lane = threadIdx.x & 63;
    int el = lane & 7;
    int q  = lane >> 3;

    float w2r[16];
#pragma unroll
    for (int i = 0; i < 16; ++i) w2r[i] = W2[16 * q + i];
    float b2s = b2[0];

    const unsigned short* vp = V + (size_t)row * 128 + 16 * q;
    uint4 va = *(const uint4*)vp;
    uint4 vb = *(const uint4*)(vp + 8);
    float vf[16];
    vf[0]  = bflo(va.x); vf[1]  = bfhi(va.x);
    vf[2]  = bflo(va.y); vf[3]  = bfhi(va.y);
    vf[4]  = bflo(va.z); vf[5]  = bfhi(va.z);
    vf[6]  = bflo(va.w); vf[7]  = bfhi(va.w);
    vf[8]  = bflo(vb.x); vf[9]  = bfhi(vb.x);
    vf[10] = bflo(vb.y); vf[11] = bfhi(vb.y);
    vf[12] = bflo(vb.z); vf[13] = bfhi(vb.z);
    vf[14] = bflo(vb.w); vf[15] = bfhi(vb.w);

    int dg = degnsp[row];
    int st = row << 6;
    int en = st + (dg < SLOT ? dg : SLOT);

    unsigned int xvr = *(const unsigned int*)(XB + (size_t)row * 128 + 2 * lane);
    float a0 = bflo(xvr), a1 = bfhi(xvr);

    for (int g = st; g < en; g += 8) {
        int e = g + el;
        bool val = (e < en);
        int s = val ? (int)esrc2[e] : 0;

        uint4 ua = *(const uint4*)(U + (size_t)s * 128 + 16 * q);
        float p = mlp16(ua, vf, w2r);
        p += __shfl_xor(p, 8);
        p += __shfl_xor(p, 16);
        p += __shfl_xor(p, 32);
        float w = val ? 1.0f / (1.0f + __expf(-(p + b2s))) : 0.0f;

#pragma unroll
        for (int j = 0; j < 8; ++j) {
            float wj = __shfl(w, j);
            int   sj = __shfl(s, j);
            unsigned int xv = *(const unsigned int*)(XB + (size_t)sj * 128 + 2 * lane);
            a0 = fmaf(wj, bflo(xv), a0);
            a1 = fmaf(wj, bfhi(xv), a1);
        }
    }

    // spill edges (correctness net; empty in practice)
    int ns = degnsp[N];
    if (ns > 0) {
        if (ns > SPILLCAP) ns = SPILLCAP;
        for (int i = 0; i < ns; ++i) {
            if (spt[i] == row) {
                int s = sps[i];  // uniform across wave
                uint4 ua = *(const uint4*)(U + (size_t)s * 128 + 16 * q);
                float p = mlp16(ua, vf, w2r);
                p += __shfl_xor(p, 8);
                p += __shfl_xor(p, 16);
                p += __shfl_xor(p, 32);
                float w = 1.0f / (1.0f + __expf(-(p + b2s)));
                unsigned int xv = *(const unsigned int*)(XB + (size_t)s * 128 + 2 * lane);
                a0 = fmaf(w, bflo(xv), a0);
                a1 = fmaf(w, bfhi(xv), a1);
            }
        }
    }

    // LayerNorm
    float sm = a0 + a1;
#pragma unroll
    for (int off = 32; off; off >>= 1) sm += __shfl_xor(sm, off);
    float mu = sm * (1.0f / 128.0f);
    float d0v = a0 - mu, d1v = a1 - mu;
    float qq = d0v * d0v + d1v * d1v;
#pragma unroll
    for (int off = 32; off; off >>= 1) qq += __shfl_xor(qq, off);
    float rstd = rsqrtf(qq * (1.0f / 128.0f) + 1e-5f);
    float2 gg = *(const float2*)(gamma + 2 * lane);
    float2 bb = *(const float2*)(beta + 2 * lane);
    float2 o;
    o.x = d0v * rstd * gg.x + bb.x;
    o.y = d1v * rstd * gg.y + bb.y;
    *(float2*)(out + (size_t)row * 128 + 2 * lane) = o;
}

extern "C" void kernel_launch(void* const* d_in, const int* in_sizes, int n_in,
                              void* d_out, int out_size, void* d_ws, size_t ws_size,
                              hipStream_t stream) {
    const float* x     = (const float*)d_in[0];
    const int*   ei    = (const int*)d_in[1];
    const float* W1    = (const float*)d_in[2];
    const float* b1    = (const float*)d_in[3];
    const float* W2    = (const float*)d_in[4];
    const float* b2    = (const float*)d_in[5];
    const float* gamma = (const float*)d_in[6];
    const float* beta  = (const float*)d_in[7];
    float* out = (float*)d_out;

    const int N = in_sizes[0] / 128;   // 50000
    const int E = in_sizes[1] / 2;     // 800000

    char* w = (char*)d_ws;
    size_t off = 0;
    auto alloc = [&](size_t bytes) {
        char* p = w + off;
        off = (off + bytes + 255) & ~(size_t)255;
        return p;
    };
    unsigned short* Bt = (unsigned short*)alloc(256 * 128 * 2);       // 64 KB
    unsigned char*  U  = (unsigned char*)alloc((size_t)N * 128);      // 6.4 MB
    unsigned short* V  = (unsigned short*)alloc((size_t)N * 128 * 2); // 12.8 MB
    unsigned short* XB = (unsigned short*)alloc((size_t)N * 128 * 2); // 12.8 MB
    int* degnsp = (int*)alloc((size_t)(N + 1) * 4);
    int* spt    = (int*)alloc((size_t)SPILLCAP * 4);
    int* sps    = (int*)alloc((size_t)SPILLCAP * 4);

    bool small_idx = (N <= 65535);
    void* esrc2v;
    if (small_idx) esrc2v = alloc((size_t)N * SLOT * 2);              // 6.4 MB ushort
    else           esrc2v = alloc((size_t)N * SLOT * 4);              // int fallback

    k_prep3<<<2048, 256, 0, stream>>>(W1, Bt, x, XB, degnsp, N * 128 / 4, N);

    dim3 ggrid((N + 63) / 64, 2);
    if (small_idx) {
        unsigned short* esrc2 = (unsigned short*)esrc2v;
        k_gemmsc<unsigned short><<<ggrid, 256, 0, stream>>>(XB, Bt, b1, U, V, ei,
                                                            degnsp, esrc2, spt, sps,
                                                            N, E);
        k_fused_slot<unsigned short><<<(N + 3) / 4, 256, 0, stream>>>(
            U, V, XB, degnsp, esrc2, spt, sps, W2, b2, gamma, beta, out, N);
    } else {
        int* esrc2 = (int*)esrc2v;
        k_gemmsc<int><<<ggrid, 256, 0, stream>>>(XB, Bt, b1, U, V, ei,
                                                 degnsp, esrc2, spt, sps, N, E);
        k_fused_slot<int><<<(N + 3) / 4, 256, 0, stream>>>(
            U, V, XB, degnsp, esrc2, spt, sps, W2, b2, gamma, beta, out, N);
    }
}

// Round 19
// 137.971 us; speedup vs baseline: 2.3055x; 1.0803x over previous
//
#include <hip/hip_runtime.h>

// ---------- helpers ----------
static __device__ __forceinline__ unsigned short f2bf(float f) {
    union { float f; unsigned int u; } c; c.f = f;
    unsigned int u = c.u;
    return (unsigned short)((u + 0x7FFFu + ((u >> 16) & 1u)) >> 16);  // RNE
}
static __device__ __forceinline__ float bflo(unsigned int uu) {
    union { unsigned int u; float f; } c; c.u = uu << 16; return c.f;
}
static __device__ __forceinline__ float bfhi(unsigned int uu) {
    union { unsigned int u; float f; } c; c.u = uu & 0xffff0000u; return c.f;
}
static __device__ __forceinline__ unsigned char f2fp8(float f) {
    int enc = __builtin_amdgcn_cvt_pk_fp8_f32(f, f, 0, false);  // OCP e4m3 on gfx950
    return (unsigned char)(enc & 0xff);
}

typedef __bf16 bf16x8 __attribute__((ext_vector_type(8)));
typedef float  f32x4  __attribute__((ext_vector_type(4)));
typedef float  f32x2  __attribute__((ext_vector_type(2)));

#define SLOT      64
#define SPILLCAP  8192
#define NXCD      8

// ---------- 16-feature MLP partial: relu(u_fp8 + v) . w2 ----------
static __device__ __forceinline__ float mlp16(uint4 ua, const float* __restrict__ vf,
                                              const float* __restrict__ w2r) {
    f32x2 d0 = __builtin_amdgcn_cvt_pk_f32_fp8(ua.x, false);
    f32x2 d1 = __builtin_amdgcn_cvt_pk_f32_fp8(ua.x, true);
    f32x2 d2 = __builtin_amdgcn_cvt_pk_f32_fp8(ua.y, false);
    f32x2 d3 = __builtin_amdgcn_cvt_pk_f32_fp8(ua.y, true);
    f32x2 d4 = __builtin_amdgcn_cvt_pk_f32_fp8(ua.z, false);
    f32x2 d5 = __builtin_amdgcn_cvt_pk_f32_fp8(ua.z, true);
    f32x2 d6 = __builtin_amdgcn_cvt_pk_f32_fp8(ua.w, false);
    f32x2 d7 = __builtin_amdgcn_cvt_pk_f32_fp8(ua.w, true);
    float p = 0.0f;
    p = fmaf(fmaxf(d0.x + vf[0],  0.f), w2r[0],  p);
    p = fmaf(fmaxf(d0.y + vf[1],  0.f), w2r[1],  p);
    p = fmaf(fmaxf(d1.x + vf[2],  0.f), w2r[2],  p);
    p = fmaf(fmaxf(d1.y + vf[3],  0.f), w2r[3],  p);
    p = fmaf(fmaxf(d2.x + vf[4],  0.f), w2r[4],  p);
    p = fmaf(fmaxf(d2.y + vf[5],  0.f), w2r[5],  p);
    p = fmaf(fmaxf(d3.x + vf[6],  0.f), w2r[6],  p);
    p = fmaf(fmaxf(d3.y + vf[7],  0.f), w2r[7],  p);
    p = fmaf(fmaxf(d4.x + vf[8],  0.f), w2r[8],  p);
    p = fmaf(fmaxf(d4.y + vf[9],  0.f), w2r[9],  p);
    p = fmaf(fmaxf(d5.x + vf[10], 0.f), w2r[10], p);
    p = fmaf(fmaxf(d5.y + vf[11], 0.f), w2r[11], p);
    p = fmaf(fmaxf(d6.x + vf[12], 0.f), w2r[12], p);
    p = fmaf(fmaxf(d6.y + vf[13], 0.f), w2r[13], p);
    p = fmaf(fmaxf(d7.x + vf[14], 0.f), w2r[14], p);
    p = fmaf(fmaxf(d7.y + vf[15], 0.f), w2r[15], p);
    return p;
}

// ---------- prep3: pack W1->Bt, x->XB bf16, zero degnsp ----------
__global__ void k_prep3(const float* __restrict__ W1, unsigned short* __restrict__ Bt,
                        const float* __restrict__ x, unsigned short* __restrict__ XB,
                        int* __restrict__ degnsp, int NH4, int N) {
    int idx = blockIdx.x * blockDim.x + threadIdx.x;
    int T = gridDim.x * blockDim.x;

    if (idx < 256 * 128) {
        int j = idx >> 7, k = idx & 127;
        int r = (j < 128) ? k : (128 + k);
        Bt[idx] = f2bf(W1[r * 128 + (j & 127)]);
    }

    for (int i = idx; i < NH4; i += T) {
        float4 f = ((const float4*)x)[i];
        ushort4 o;
        o.x = f2bf(f.x); o.y = f2bf(f.y); o.z = f2bf(f.z); o.w = f2bf(f.w);
        ((ushort4*)XB)[i] = o;
    }

    for (int i = idx; i <= N; i += T) degnsp[i] = 0;
}

// ---------- gemm + XCD-partitioned slot-scatter tail (R15-proven) ----------
// grid (ceil(M/64), 4), acc[4]/wave. y=0,1 -> U fp8; y=2,3 -> V bf16 + b1 fold.
// Tail: blocks of class c (= linear block id & 7, the default XCD round-robin)
// scatter ONLY edges with target in range c -> each esrc2/degnsp line is written
// by a single XCD class, stays L2-resident, fills fully before one writeback.
template <typename IT>
__global__ __launch_bounds__(256) void k_gemmsc(const unsigned short* __restrict__ XB,
                                                const unsigned short* __restrict__ Bt,
                                                const float* __restrict__ b1,
                                                unsigned char* __restrict__ U,
                                                unsigned short* __restrict__ V,
                                                const int* __restrict__ ei,
                                                int* __restrict__ degnsp,
                                                IT* __restrict__ esrc2,
                                                int* __restrict__ spt,
                                                int* __restrict__ sps,
                                                int M, int E) {
    int wave = threadIdx.x >> 6, lane = threadIdx.x & 63;
    int row0 = blockIdx.x * 64 + wave * 16;
    int col0 = blockIdx.y * 64;
    int lr = lane & 15;
    int lk = (lane >> 4) << 3;

    f32x4 acc[4] = {};
    int arow = row0 + lr;
    bool in = (arow < M);
    const unsigned short* xr = XB + (size_t)arow * 128;

#pragma unroll
    for (int kk = 0; kk < 4; ++kk) {
        int k = kk * 32 + lk;
        bf16x8 a = {};
        if (in) a = *(const bf16x8*)(xr + k);
#pragma unroll
        for (int nf = 0; nf < 4; ++nf) {
            int col = col0 + nf * 16 + lr;
            bf16x8 b = *(const bf16x8*)(Bt + col * 128 + k);
            acc[nf] = __builtin_amdgcn_mfma_f32_16x16x32_bf16(a, b, acc[nf], 0, 0, 0);
        }
    }
    // C/D: col = lane&15, row = (lane>>4)*4 + reg
    int rb = row0 + ((lane >> 4) << 2);
    if (col0 < 128) {
#pragma unroll
        for (int nf = 0; nf < 4; ++nf) {
            int feat = col0 + nf * 16 + lr;
#pragma unroll
            for (int r = 0; r < 4; ++r) {
                int node = rb + r;
                if (node < M) U[(size_t)node * 128 + feat] = f2fp8(acc[nf][r]);
            }
        }
    } else {
#pragma unroll
        for (int nf = 0; nf < 4; ++nf) {
            int feat = col0 + nf * 16 + lr - 128;
            float bias = b1[feat];
#pragma unroll
            for (int r = 0; r < 4; ++r) {
                int node = rb + r;
                if (node < M) V[(size_t)node * 128 + feat] = f2bf(acc[nf][r] + bias);
            }
        }
    }

    // ---- XCD-partitioned slot-scatter tail ----
    int nblk = gridDim.x * gridDim.y;
    int lin  = blockIdx.y * gridDim.x + blockIdx.x;
    int cls  = lin & (NXCD - 1);                 // XCD class (heuristic mapping)
    int bidc = lin >> 3;                          // block index within class
    int nbc  = (nblk - cls + NXCD - 1) >> 3;      // blocks in this class
    int tid  = bidc * blockDim.x + (int)threadIdx.x;
    int T    = nbc * blockDim.x;
    int N    = M;
    int t0 = (int)(((long long)N * cls) >> 3);
    int t1 = (int)(((long long)N * (cls + 1)) >> 3);

    for (int e = tid; e < E; e += T) {
        int t = ei[E + e];
        if (t < t0 || t >= t1) continue;          // not this class's target range
        int s = ei[e];
        int r = atomicAdd(degnsp + t, 1);
        if (r < SLOT) {
            esrc2[((size_t)t << 6) + r] = (IT)s;
        } else {
            int sp = atomicAdd(degnsp + N, 1);
            if (sp < SPILLCAP) { spt[sp] = t; sps[sp] = s; }
        }
    }
}

// ---------- fused (slotted): per-target weights + aggregate + LayerNorm ----------
template <typename IT>
__global__ __launch_bounds__(256) void k_fused_slot(const unsigned char* __restrict__ U,
                                                    const unsigned short* __restrict__ V,
                                                    const unsigned short* __restrict__ XB,
                                                    const int* __restrict__ degnsp,
                                                    const IT* __restrict__ esrc2,
                                                    const int* __restrict__ spt,
                                                    const int* __restrict__ sps,
                                                    const float* __restrict__ W2,
                                                    const float* __restrict__ b2,
                                                    const float* __restrict__ gamma,
                                                    const float* __restrict__ beta,
                                                    float* __restrict__ out, int N) {
    int row = blockIdx.x * 4 + (threadIdx.x >> 6);
    if (row >= N) return;
    int lane = threadIdx.x & 63;
    int el = lane & 7;
    int q  = lane >> 3;

    float w2r[16];
#pragma unroll
    for (int i = 0; i < 16; ++i) w2r[i] = W2[16 * q + i];
    float b2s = b2[0];

    const unsigned short* vp = V + (size_t)row * 128 + 16 * q;
    uint4 va = *(const uint4*)vp;
    uint4 vb = *(const uint4*)(vp + 8);
    float vf[16];
    vf[0]  = bflo(va.x); vf[1]  = bfhi(va.x);
    vf[2]  = bflo(va.y); vf[3]  = bfhi(va.y);
    vf[4]  = bflo(va.z); vf[5]  = bfhi(va.z);
    vf[6]  = bflo(va.w); vf[7]  = bfhi(va.w);
    vf[8]  = bflo(vb.x); vf[9]  = bfhi(vb.x);
    vf[10] = bflo(vb.y); vf[11] = bfhi(vb.y);
    vf[12] = bflo(vb.z); vf[13] = bfhi(vb.z);
    vf[14] = bflo(vb.w); vf[15] = bfhi(vb.w);

    int dg = degnsp[row];
    int st = row << 6;
    int en = st + (dg < SLOT ? dg : SLOT);

    unsigned int xvr = *(const unsigned int*)(XB + (size_t)row * 128 + 2 * lane);
    float a0 = bflo(xvr), a1 = bfhi(xvr);

    for (int g = st; g < en; g += 8) {
        int e = g + el;
        bool val = (e < en);
        int s = val ? (int)esrc2[e] : 0;

        uint4 ua = *(const uint4*)(U + (size_t)s * 128 + 16 * q);
        float p = mlp16(ua, vf, w2r);
        p += __shfl_xor(p, 8);
        p += __shfl_xor(p, 16);
        p += __shfl_xor(p, 32);
        float w = val ? 1.0f / (1.0f + __expf(-(p + b2s))) : 0.0f;

#pragma unroll
        for (int j = 0; j < 8; ++j) {
            float wj = __shfl(w, j);
            int   sj = __shfl(s, j);
            unsigned int xv = *(const unsigned int*)(XB + (size_t)sj * 128 + 2 * lane);
            a0 = fmaf(wj, bflo(xv), a0);
            a1 = fmaf(wj, bfhi(xv), a1);
        }
    }

    // spill edges (correctness net; empty in practice)
    int ns = degnsp[N];
    if (ns > 0) {
        if (ns > SPILLCAP) ns = SPILLCAP;
        for (int i = 0; i < ns; ++i) {
            if (spt[i] == row) {
                int s = sps[i];  // uniform across wave
                uint4 ua = *(const uint4*)(U + (size_t)s * 128 + 16 * q);
                float p = mlp16(ua, vf, w2r);
                p += __shfl_xor(p, 8);
                p += __shfl_xor(p, 16);
                p += __shfl_xor(p, 32);
                float w = 1.0f / (1.0f + __expf(-(p + b2s)));
                unsigned int xv = *(const unsigned int*)(XB + (size_t)s * 128 + 2 * lane);
                a0 = fmaf(w, bflo(xv), a0);
                a1 = fmaf(w, bfhi(xv), a1);
            }
        }
    }

    // LayerNorm
    float sm = a0 + a1;
#pragma unroll
    for (int off = 32; off; off >>= 1) sm += __shfl_xor(sm, off);
    float mu = sm * (1.0f / 128.0f);
    float d0v = a0 - mu, d1v = a1 - mu;
    float qq = d0v * d0v + d1v * d1v;
#pragma unroll
    for (int off = 32; off; off >>= 1) qq += __shfl_xor(qq, off);
    float rstd = rsqrtf(qq * (1.0f / 128.0f) + 1e-5f);
    float2 gg = *(const float2*)(gamma + 2 * lane);
    float2 bb = *(const float2*)(beta + 2 * lane);
    float2 o;
    o.x = d0v * rstd * gg.x + bb.x;
    o.y = d1v * rstd * gg.y + bb.y;
    *(float2*)(out + (size_t)row * 128 + 2 * lane) = o;
}

extern "C" void kernel_launch(void* const* d_in, const int* in_sizes, int n_in,
                              void* d_out, int out_size, void* d_ws, size_t ws_size,
                              hipStream_t stream) {
    const float* x     = (const float*)d_in[0];
    const int*   ei    = (const int*)d_in[1];
    const float* W1    = (const float*)d_in[2];
    const float* b1    = (const float*)d_in[3];
    const float* W2    = (const float*)d_in[4];
    const float* b2    = (const float*)d_in[5];
    const float* gamma = (const float*)d_in[6];
    const float* beta  = (const float*)d_in[7];
    float* out = (float*)d_out;

    const int N = in_sizes[0] / 128;   // 50000
    const int E = in_sizes[1] / 2;     // 800000

    char* w = (char*)d_ws;
    size_t off = 0;
    auto alloc = [&](size_t bytes) {
        char* p = w + off;
        off = (off + bytes + 255) & ~(size_t)255;
        return p;
    };
    unsigned short* Bt = (unsigned short*)alloc(256 * 128 * 2);       // 64 KB
    unsigned char*  U  = (unsigned char*)alloc((size_t)N * 128);      // 6.4 MB
    unsigned short* V  = (unsigned short*)alloc((size_t)N * 128 * 2); // 12.8 MB
    unsigned short* XB = (unsigned short*)alloc((size_t)N * 128 * 2); // 12.8 MB
    int* degnsp = (int*)alloc((size_t)(N + 1) * 4);
    int* spt    = (int*)alloc((size_t)SPILLCAP * 4);
    int* sps    = (int*)alloc((size_t)SPILLCAP * 4);

    bool small_idx = (N <= 65535);
    void* esrc2v;
    if (small_idx) esrc2v = alloc((size_t)N * SLOT * 2);              // 6.4 MB ushort
    else           esrc2v = alloc((size_t)N * SLOT * 4);              // int fallback

    k_prep3<<<2048, 256, 0, stream>>>(W1, Bt, x, XB, degnsp, N * 128 / 4, N);

    dim3 ggrid((N + 63) / 64, 4);
    if (small_idx) {
        unsigned short* esrc2 = (unsigned short*)esrc2v;
        k_gemmsc<unsigned short><<<ggrid, 256, 0, stream>>>(XB, Bt, b1, U, V, ei,
                                                            degnsp, esrc2, spt, sps,
                                                            N, E);
        k_fused_slot<unsigned short><<<(N + 3) / 4, 256, 0, stream>>>(
            U, V, XB, degnsp, esrc2, spt, sps, W2, b2, gamma, beta, out, N);
    } else {
        int* esrc2 = (int*)esrc2v;
        k_gemmsc<int><<<ggrid, 256, 0, stream>>>(XB, Bt, b1, U, V, ei,
                                                 degnsp, esrc2, spt, sps, N, E);
        k_fused_slot<int><<<(N + 3) / 4, 256, 0, stream>>>(
            U, V, XB, degnsp, esrc2, spt, sps, W2, b2, gamma, beta, out, N);
    }
}